// Round 1
// baseline (152.837 us; speedup 1.0000x reference)
//
#include <hip/hip_runtime.h>
#include <math.h>

#define NL 371
#define LUTN 4096            // LUT nodes; (LUTN-1) intervals over s in [0,1]
#define NPIX (1024*1024)
#define NB 8
#define STRESS_MAG 72000000.0f

// ---- ordered-uint encoding for float atomics (handles negatives) ----
__device__ __forceinline__ unsigned enc(float f) {
    unsigned u = __float_as_uint(f);
    return (u & 0x80000000u) ? ~u : (u | 0x80000000u);
}
__device__ __forceinline__ float dec(unsigned k) {
    unsigned u = (k & 0x80000000u) ? (k ^ 0x80000000u) : ~k;
    return __uint_as_float(u);
}

__global__ void k_init(unsigned* __restrict__ minU, unsigned* __restrict__ maxU,
                       unsigned* __restrict__ isoU) {
    int t = threadIdx.x;
    if (t < NB) { minU[t] = 0xFFFFFFFFu; maxU[t] = 0u; isoU[t] = 0u; }
}

__global__ __launch_bounds__(256) void k_minmax(const float4* __restrict__ x,
                                                unsigned* __restrict__ minU,
                                                unsigned* __restrict__ maxU) {
    int b = blockIdx.y;
    const float4* p = x + (size_t)b * (NPIX / 4);
    float mn = 3.4e38f, mx = -3.4e38f;
    for (int i = blockIdx.x * blockDim.x + threadIdx.x; i < NPIX / 4;
         i += gridDim.x * blockDim.x) {
        float4 v = p[i];
        mn = fminf(mn, fminf(fminf(v.x, v.y), fminf(v.z, v.w)));
        mx = fmaxf(mx, fmaxf(fmaxf(v.x, v.y), fmaxf(v.z, v.w)));
    }
    for (int off = 32; off >= 1; off >>= 1) {
        mn = fminf(mn, __shfl_down(mn, off));
        mx = fmaxf(mx, __shfl_down(mx, off));
    }
    __shared__ float smn[4], smx[4];
    int wid = threadIdx.x >> 6;
    if ((threadIdx.x & 63) == 0) { smn[wid] = mn; smx[wid] = mx; }
    __syncthreads();
    if (threadIdx.x == 0) {
        for (int w = 1; w < 4; ++w) { mn = fminf(mn, smn[w]); mx = fmaxf(mx, smx[w]); }
        atomicMin(&minU[b], enc(mn));
        atomicMax(&maxU[b], enc(mx));
    }
}

// Build LUT: f_c(s) = sum_i w[i][c] * 0.5 * (1 - cos((coef/lam_i) * s * MAG))
__global__ __launch_bounds__(256) void k_lut(const float* __restrict__ w,
                                             float4* __restrict__ lut) {
    int j = blockIdx.x * blockDim.x + threadIdx.x;
    if (j >= LUTN) return;
    float s  = (float)j * (1.0f / (float)(LUTN - 1));
    float sr = s * STRESS_MAG;
    const float coef = (float)(2.0 * M_PI * 0.01 * 3.5e-12 / 1e-9);
    float a0 = 0.f, a1 = 0.f, a2 = 0.f;
    for (int i = 0; i < NL; ++i) {
        float lam = 390.0f + (float)i;           // linspace(390,760,371) step=1.0
        float ph  = (coef / lam) * sr;
        float t   = 0.5f * (1.0f - cosf(ph));
        a0 = fmaf(w[i * 3 + 0], t, a0);
        a1 = fmaf(w[i * 3 + 1], t, a1);
        a2 = fmaf(w[i * 3 + 2], t, a2);
    }
    lut[j] = make_float4(a0, a1, a2, 0.0f);
}

__device__ __forceinline__ void lut_interp(const float4* slut, float s,
                                           float& i0, float& i1, float& i2) {
    float t = s * (float)(LUTN - 1);
    int j = (int)t;
    j = min(j, LUTN - 2);
    float fr = t - (float)j;
    float4 A = slut[j];
    float4 B = slut[j + 1];
    i0 = fmaf(fr, B.x - A.x, A.x);
    i1 = fmaf(fr, B.y - A.y, A.y);
    i2 = fmaf(fr, B.z - A.z, A.z);
}

// Pass 1: write stress_nomal, compute per-batch max of isochromatic via LUT
__global__ __launch_bounds__(256) void k_pass1(const float4* __restrict__ x,
                                               const float4* __restrict__ lut,
                                               const unsigned* __restrict__ minU,
                                               const unsigned* __restrict__ maxU,
                                               unsigned* __restrict__ isoU,
                                               float4* __restrict__ snorm) {
    __shared__ float4 slut[LUTN];   // 64 KB
    for (int i = threadIdx.x; i < LUTN; i += blockDim.x) slut[i] = lut[i];
    __syncthreads();
    int b = blockIdx.y;
    float mn  = dec(minU[b]);
    float inv = 1.0f / (dec(maxU[b]) - mn);
    const float4* p = x + (size_t)b * (NPIX / 4);
    float4* q = snorm + (size_t)b * (NPIX / 4);
    float m = 0.0f;
    for (int i = blockIdx.x * blockDim.x + threadIdx.x; i < NPIX / 4;
         i += gridDim.x * blockDim.x) {
        float4 v = p[i];
        float4 s;
        s.x = (v.x - mn) * inv; s.y = (v.y - mn) * inv;
        s.z = (v.z - mn) * inv; s.w = (v.w - mn) * inv;
        q[i] = s;
        float i0, i1, i2;
        lut_interp(slut, s.x, i0, i1, i2);
        m = fmaxf(m, fmaxf(fmaxf(i0, i1), i2));
        lut_interp(slut, s.y, i0, i1, i2);
        m = fmaxf(m, fmaxf(fmaxf(i0, i1), i2));
        lut_interp(slut, s.z, i0, i1, i2);
        m = fmaxf(m, fmaxf(fmaxf(i0, i1), i2));
        lut_interp(slut, s.w, i0, i1, i2);
        m = fmaxf(m, fmaxf(fmaxf(i0, i1), i2));
    }
    for (int off = 32; off >= 1; off >>= 1)
        m = fmaxf(m, __shfl_down(m, off));
    __shared__ float sm[4];
    int wid = threadIdx.x >> 6;
    if ((threadIdx.x & 63) == 0) sm[wid] = m;
    __syncthreads();
    if (threadIdx.x == 0) {
        for (int w = 1; w < 4; ++w) m = fmaxf(m, sm[w]);
        atomicMax(&isoU[b], enc(m));
    }
}

// Pass 2: read snorm, LUT-interp again, scale by 1/isoMax, write iso planes
__global__ __launch_bounds__(256) void k_pass2(const float4* __restrict__ snorm,
                                               const float4* __restrict__ lut,
                                               const unsigned* __restrict__ isoU,
                                               float4* __restrict__ iso) {
    __shared__ float4 slut[LUTN];   // 64 KB
    for (int i = threadIdx.x; i < LUTN; i += blockDim.x) slut[i] = lut[i];
    __syncthreads();
    int b = blockIdx.y;
    float invIso = 1.0f / dec(isoU[b]);
    const float4* p = snorm + (size_t)b * (NPIX / 4);
    float4* q0 = iso + (size_t)(b * 3 + 0) * (NPIX / 4);
    float4* q1 = iso + (size_t)(b * 3 + 1) * (NPIX / 4);
    float4* q2 = iso + (size_t)(b * 3 + 2) * (NPIX / 4);
    for (int i = blockIdx.x * blockDim.x + threadIdx.x; i < NPIX / 4;
         i += gridDim.x * blockDim.x) {
        float4 s = p[i];
        float4 r0, r1, r2;
        float i0, i1, i2;
        lut_interp(slut, s.x, i0, i1, i2);
        r0.x = i0 * invIso; r1.x = i1 * invIso; r2.x = i2 * invIso;
        lut_interp(slut, s.y, i0, i1, i2);
        r0.y = i0 * invIso; r1.y = i1 * invIso; r2.y = i2 * invIso;
        lut_interp(slut, s.z, i0, i1, i2);
        r0.z = i0 * invIso; r1.z = i1 * invIso; r2.z = i2 * invIso;
        lut_interp(slut, s.w, i0, i1, i2);
        r0.w = i0 * invIso; r1.w = i1 * invIso; r2.w = i2 * invIso;
        q0[i] = r0; q1[i] = r1; q2[i] = r2;
    }
}

extern "C" void kernel_launch(void* const* d_in, const int* in_sizes, int n_in,
                              void* d_out, int out_size, void* d_ws, size_t ws_size,
                              hipStream_t stream) {
    const float4* stress = (const float4*)d_in[0];      // [8,1,1024,1024] f32
    const float*  ssint  = (const float*)d_in[1];       // [371,3] f32

    float* out   = (float*)d_out;
    float4* iso  = (float4*)out;                                    // 8*3*1M
    float4* snorm = (float4*)(out + (size_t)NB * 3 * NPIX);         // 8*1M

    float4*   lut  = (float4*)d_ws;                                 // 64 KB
    unsigned* minU = (unsigned*)((char*)d_ws + (size_t)LUTN * 16);
    unsigned* maxU = minU + NB;
    unsigned* isoU = maxU + NB;

    k_init<<<dim3(1), dim3(64), 0, stream>>>(minU, maxU, isoU);
    k_minmax<<<dim3(32, NB), dim3(256), 0, stream>>>(stress, minU, maxU);
    k_lut<<<dim3(LUTN / 256), dim3(256), 0, stream>>>(ssint, lut);
    k_pass1<<<dim3(64, NB), dim3(256), 0, stream>>>(stress, lut, minU, maxU, isoU, snorm);
    k_pass2<<<dim3(64, NB), dim3(256), 0, stream>>>(snorm, lut, isoU, iso);
}

// Round 2
// 83.922 us; speedup vs baseline: 1.8212x; 1.8212x over previous
//
#include <hip/hip_runtime.h>
#include <math.h>

#define NL 371
#define LUTN 4096            // LUT nodes; (LUTN-1) intervals over s in [0,1]
#define NPIX (1024*1024)
#define NB 8
#define STRESS_MAG 72000000.0f

// ---- ordered-uint encoding for float atomics (handles negatives) ----
__device__ __forceinline__ unsigned enc(float f) {
    unsigned u = __float_as_uint(f);
    return (u & 0x80000000u) ? ~u : (u | 0x80000000u);
}
__device__ __forceinline__ float dec(unsigned k) {
    unsigned u = (k & 0x80000000u) ? (k ^ 0x80000000u) : ~k;
    return __uint_as_float(u);
}

// Build LUT: f_c(s) = sum_i w[i][c] * 0.5 * (1 - cos(2*pi * k_rev[i] * s))
// k_rev[i] = H*C/1e-9 * MAG / lam_i  (revolutions per unit s; max ~6.5)
// Grid: 64 blocks x 256 threads. Each block: 64 j-values x 4 lambda-partitions.
// Also re-inits the atomic slots (block 0) so k_init is not needed.
__global__ __launch_bounds__(256) void k_lut(const float* __restrict__ w,
                                             float4* __restrict__ lut,
                                             unsigned* __restrict__ minU,
                                             unsigned* __restrict__ maxU,
                                             unsigned* __restrict__ isoU) {
    if (blockIdx.x == 0 && threadIdx.x < NB) {
        minU[threadIdx.x] = 0xFFFFFFFFu;
        maxU[threadIdx.x] = 0u;
        isoU[threadIdx.x] = 0u;
    }
    __shared__ float kw[NL], w0[NL], w1[NL], w2[NL];
    const float coef_rev = (float)(0.01 * 3.5e-12 / 1e-9) * STRESS_MAG; // 2520
    for (int i = threadIdx.x; i < NL; i += blockDim.x) {
        float lam = 390.0f + (float)i;      // linspace(390,760,371), step 1.0
        kw[i] = coef_rev / lam;
        w0[i] = w[i * 3 + 0];
        w1[i] = w[i * 3 + 1];
        w2[i] = w[i * 3 + 2];
    }
    __syncthreads();

    int jj   = threadIdx.x & 63;
    int part = threadIdx.x >> 6;            // 0..3 lambda partition
    int j    = blockIdx.x * 64 + jj;
    float s  = (float)j * (1.0f / (float)(LUTN - 1));

    float a0 = 0.f, a1 = 0.f, a2 = 0.f;
    for (int i = part; i < NL; i += 4) {
        float r = kw[i] * s;                // revolutions, <= ~6.5
        r = r - floorf(r);                  // reduce to [0,1)
        float c = __builtin_amdgcn_cosf(r); // v_cos_f32: cos(2*pi*r)
        float t = fmaf(-0.5f, c, 0.5f);     // 0.5*(1-c)
        a0 = fmaf(w0[i], t, a0);
        a1 = fmaf(w1[i], t, a1);
        a2 = fmaf(w2[i], t, a2);
    }

    __shared__ float r0[256], r1[256], r2[256];
    r0[threadIdx.x] = a0; r1[threadIdx.x] = a1; r2[threadIdx.x] = a2;
    __syncthreads();
    if (part == 0) {
        int t = jj;
        a0 = (r0[t] + r0[t + 64]) + (r0[t + 128] + r0[t + 192]);
        a1 = (r1[t] + r1[t + 64]) + (r1[t + 128] + r1[t + 192]);
        a2 = (r2[t] + r2[t + 64]) + (r2[t + 128] + r2[t + 192]);
        lut[j] = make_float4(a0, a1, a2, 0.0f);
    }
}

__global__ __launch_bounds__(256) void k_minmax(const float4* __restrict__ x,
                                                unsigned* __restrict__ minU,
                                                unsigned* __restrict__ maxU) {
    int b = blockIdx.y;
    const float4* p = x + (size_t)b * (NPIX / 4);
    float mn = 3.4e38f, mx = -3.4e38f;
    for (int i = blockIdx.x * blockDim.x + threadIdx.x; i < NPIX / 4;
         i += gridDim.x * blockDim.x) {
        float4 v = p[i];
        mn = fminf(mn, fminf(fminf(v.x, v.y), fminf(v.z, v.w)));
        mx = fmaxf(mx, fmaxf(fmaxf(v.x, v.y), fmaxf(v.z, v.w)));
    }
    for (int off = 32; off >= 1; off >>= 1) {
        mn = fminf(mn, __shfl_down(mn, off));
        mx = fmaxf(mx, __shfl_down(mx, off));
    }
    __shared__ float smn[4], smx[4];
    int wid = threadIdx.x >> 6;
    if ((threadIdx.x & 63) == 0) { smn[wid] = mn; smx[wid] = mx; }
    __syncthreads();
    if (threadIdx.x == 0) {
        for (int w = 1; w < 4; ++w) { mn = fminf(mn, smn[w]); mx = fmaxf(mx, smx[w]); }
        atomicMin(&minU[b], enc(mn));
        atomicMax(&maxU[b], enc(mx));
    }
}

__device__ __forceinline__ void lut_interp(const float4* slut, float s,
                                           float& i0, float& i1, float& i2) {
    float t = s * (float)(LUTN - 1);
    int j = (int)t;
    j = min(j, LUTN - 2);
    float fr = t - (float)j;
    float4 A = slut[j];
    float4 B = slut[j + 1];
    i0 = fmaf(fr, B.x - A.x, A.x);
    i1 = fmaf(fr, B.y - A.y, A.y);
    i2 = fmaf(fr, B.z - A.z, A.z);
}

// Pass 1: write stress_nomal, compute per-batch max of isochromatic via LUT
__global__ __launch_bounds__(256) void k_pass1(const float4* __restrict__ x,
                                               const float4* __restrict__ lut,
                                               const unsigned* __restrict__ minU,
                                               const unsigned* __restrict__ maxU,
                                               unsigned* __restrict__ isoU,
                                               float4* __restrict__ snorm) {
    __shared__ float4 slut[LUTN];   // 64 KB
    for (int i = threadIdx.x; i < LUTN; i += blockDim.x) slut[i] = lut[i];
    __syncthreads();
    int b = blockIdx.y;
    float mn  = dec(minU[b]);
    float inv = 1.0f / (dec(maxU[b]) - mn);
    const float4* p = x + (size_t)b * (NPIX / 4);
    float4* q = snorm + (size_t)b * (NPIX / 4);
    float m = 0.0f;
    for (int i = blockIdx.x * blockDim.x + threadIdx.x; i < NPIX / 4;
         i += gridDim.x * blockDim.x) {
        float4 v = p[i];
        float4 s;
        s.x = (v.x - mn) * inv; s.y = (v.y - mn) * inv;
        s.z = (v.z - mn) * inv; s.w = (v.w - mn) * inv;
        q[i] = s;
        float i0, i1, i2;
        lut_interp(slut, s.x, i0, i1, i2);
        m = fmaxf(m, fmaxf(fmaxf(i0, i1), i2));
        lut_interp(slut, s.y, i0, i1, i2);
        m = fmaxf(m, fmaxf(fmaxf(i0, i1), i2));
        lut_interp(slut, s.z, i0, i1, i2);
        m = fmaxf(m, fmaxf(fmaxf(i0, i1), i2));
        lut_interp(slut, s.w, i0, i1, i2);
        m = fmaxf(m, fmaxf(fmaxf(i0, i1), i2));
    }
    for (int off = 32; off >= 1; off >>= 1)
        m = fmaxf(m, __shfl_down(m, off));
    __shared__ float sm[4];
    int wid = threadIdx.x >> 6;
    if ((threadIdx.x & 63) == 0) sm[wid] = m;
    __syncthreads();
    if (threadIdx.x == 0) {
        for (int w = 1; w < 4; ++w) m = fmaxf(m, sm[w]);
        atomicMax(&isoU[b], enc(m));
    }
}

// Pass 2: read snorm, LUT-interp again, scale by 1/isoMax, write iso planes
__global__ __launch_bounds__(256) void k_pass2(const float4* __restrict__ snorm,
                                               const float4* __restrict__ lut,
                                               const unsigned* __restrict__ isoU,
                                               float4* __restrict__ iso) {
    __shared__ float4 slut[LUTN];   // 64 KB
    for (int i = threadIdx.x; i < LUTN; i += blockDim.x) slut[i] = lut[i];
    __syncthreads();
    int b = blockIdx.y;
    float invIso = 1.0f / dec(isoU[b]);
    const float4* p = snorm + (size_t)b * (NPIX / 4);
    float4* q0 = iso + (size_t)(b * 3 + 0) * (NPIX / 4);
    float4* q1 = iso + (size_t)(b * 3 + 1) * (NPIX / 4);
    float4* q2 = iso + (size_t)(b * 3 + 2) * (NPIX / 4);
    for (int i = blockIdx.x * blockDim.x + threadIdx.x; i < NPIX / 4;
         i += gridDim.x * blockDim.x) {
        float4 s = p[i];
        float4 r0, r1, r2;
        float i0, i1, i2;
        lut_interp(slut, s.x, i0, i1, i2);
        r0.x = i0 * invIso; r1.x = i1 * invIso; r2.x = i2 * invIso;
        lut_interp(slut, s.y, i0, i1, i2);
        r0.y = i0 * invIso; r1.y = i1 * invIso; r2.y = i2 * invIso;
        lut_interp(slut, s.z, i0, i1, i2);
        r0.z = i0 * invIso; r1.z = i1 * invIso; r2.z = i2 * invIso;
        lut_interp(slut, s.w, i0, i1, i2);
        r0.w = i0 * invIso; r1.w = i1 * invIso; r2.w = i2 * invIso;
        q0[i] = r0; q1[i] = r1; q2[i] = r2;
    }
}

extern "C" void kernel_launch(void* const* d_in, const int* in_sizes, int n_in,
                              void* d_out, int out_size, void* d_ws, size_t ws_size,
                              hipStream_t stream) {
    const float4* stress = (const float4*)d_in[0];      // [8,1,1024,1024] f32
    const float*  ssint  = (const float*)d_in[1];       // [371,3] f32

    float* out    = (float*)d_out;
    float4* iso   = (float4*)out;                                   // 8*3*1M
    float4* snorm = (float4*)(out + (size_t)NB * 3 * NPIX);         // 8*1M

    float4*   lut  = (float4*)d_ws;                                 // 64 KB
    unsigned* minU = (unsigned*)((char*)d_ws + (size_t)LUTN * 16);
    unsigned* maxU = minU + NB;
    unsigned* isoU = maxU + NB;

    k_lut<<<dim3(LUTN / 64), dim3(256), 0, stream>>>(ssint, lut, minU, maxU, isoU);
    k_minmax<<<dim3(32, NB), dim3(256), 0, stream>>>(stress, minU, maxU);
    k_pass1<<<dim3(64, NB), dim3(256), 0, stream>>>(stress, lut, minU, maxU, isoU, snorm);
    k_pass2<<<dim3(64, NB), dim3(256), 0, stream>>>(snorm, lut, isoU, iso);
}